// Round 5
// baseline (318.842 us; speedup 1.0000x reference)
//
#include <hip/hip_runtime.h>

typedef __attribute__((ext_vector_type(8))) short short8;
typedef __attribute__((ext_vector_type(4))) float f32x4;

#define Q3 51380224      // 8192*6272

// ---- LDS layout (u16 elements) — R3-proven, fully initialized ----
#define XB_OFF 0          // xb [64][136]  (rows 0..50 staged; 51-63 junk->TRASH only)
#define XB_ST 136
#define Q_OFF 8704        // q [4][64][40], rows 49-63 zeroed
#define QK_H 2560
#define QK_ST 40
#define K_OFF 18944       // k [4][64][40], rows 49-63 zeroed
#define VT_OFF 29184      // vT [4][32][72], fully zeroed then filled
#define VT_H 2304
#define VT_ST 72
#define TRASH 38400       // scatter sentinel (dead element)
#define LDS_EL 38408      // 76,816 B -> 2 blocks/CU
// P overlays q+k after the post-QK barrier: [4][64][72] at Q_OFF (ends 27136)
#define P_OFF 8704
#define P_ST 72
#define AOUT_OFF 0        // Aout [49][136] overlays xb
// ---- ws layout (bytes) ----
// wq bf16[384][128] @0 ; pw bf16[128][128] @98304 ; stab u16[3][384][64] @131072 ;
// T fp32[64][4][64][64] @278528

__device__ __forceinline__ unsigned short f2bf(float f) {
    unsigned int u = __float_as_uint(f);
    u += 0x7FFFu + ((u >> 16) & 1u);   // RNE
    return (unsigned short)(u >> 16);
}

__global__ __launch_bounds__(256) void prep(
    const float* __restrict__ qkv_w, const float* __restrict__ proj_w,
    const float* __restrict__ mask, const float* __restrict__ rpt,
    unsigned short* __restrict__ wq, unsigned short* __restrict__ pw,
    unsigned short* __restrict__ stab, float* __restrict__ T)
{
    int t = blockIdx.x * 256 + threadIdx.x;
    if (t < 49152) {                       // wq[c][k] = bf16(qkv_w[k][c])
        int c = t >> 7, k = t & 127;
        wq[t] = f2bf(qkv_w[k * 384 + c]);
        return;
    }
    t -= 49152;
    if (t < 16384) {                       // pw[c][k] = bf16(proj_w[k][c])
        int c = t >> 7, k = t & 127;
        pw[t] = f2bf(proj_w[k * 128 + c]);
        return;
    }
    t -= 16384;
    if (t < 73728) {                       // stab[b3][C][R] -> LDS element index
        int R = t & 63;
        int b3 = t / (384 * 64);
        int C = (t - b3 * 384 * 64) >> 6;
        unsigned short el = TRASH;
        if (R <= 50) {
            int run = R >= 34 ? 2 : (R >= 17 ? 1 : 0);
            int sh = run == 0 ? b3 : (run == 1 ? b3 + 2 : b3 + 1);
            int offs = 128 * (sh % 3);
            int t2 = (R - run * 17) * 384 + C - offs;
            if (t2 >= 0 && t2 < 6272) {
                int h = t2 / 1568;
                int rem = t2 - h * 1568;
                int n = rem >> 5, d = rem & 31;
                el = (run == 2) ? (unsigned short)(VT_OFF + h * VT_H + d * VT_ST + n)
                   : (unsigned short)((run == 1 ? K_OFF : Q_OFF) + h * QK_H + n * QK_ST + d);
            }
        }
        stab[t] = el;
        return;
    }
    t -= 73728;
    if (t < 64 * 4 * 64 * 64) {            // T[w][h][i][j] = log2e*(bias+mask), pads
        int j = t & 63, i = (t >> 6) & 63, h = (t >> 12) & 3, w = t >> 14;
        float v;
        if (j >= 49) v = -1e30f;
        else if (i >= 49) v = 0.f;
        else {
            int ri = i / 7, ci = i - ri * 7, rj = j / 7, cj = j - rj * 7;
            int idx = (ri - rj + 6) * 13 + (ci - cj + 6);
            v = (rpt[idx * 4 + h] + mask[(w * 49 + i) * 49 + j]) * 1.4426950408889634f;
        }
        T[t] = v;
    }
}

__global__ __launch_bounds__(512, 4) void winattn(
    const float* __restrict__ x,
    const unsigned short* __restrict__ wq, const unsigned short* __restrict__ pw,
    const unsigned short* __restrict__ stab, const float* __restrict__ T,
    const float* __restrict__ qkv_b, const float* __restrict__ proj_b,
    float* __restrict__ out)
{
    __shared__ unsigned short lds[LDS_EL];
    unsigned int* ldsw = (unsigned int*)lds;
    const int b = blockIdx.x;
    const int tid = threadIdx.x;
    const int wid = tid >> 6;
    const int lane = tid & 63;
    const int l15 = lane & 15;
    const int lq = lane >> 4;
    const f32x4 zero = {0.f, 0.f, 0.f, 0.f};
    const float qscale = 0.17677669529663687f * 1.4426950408889634f; // scale*log2e
    const int b3 = b % 3;

    const int base0 = b * 6272;
    const int r0_0 = base0 / 384;
    const int r0_1 = (Q3 + base0) / 384;
    const int r0_2 = (2 * Q3 + base0) / 384;

    // ---- zero vT (9216 el) and q/k pad rows 49-63 ----
    for (int t = tid; t < 4608; t += 512) ldsw[(VT_OFF >> 1) + t] = 0u;
    for (int t = tid; t < 2400; t += 512) {
        int run = t / 300, rem = t - run * 300;
        int h = run & 3, reg = run >> 2;
        ldsw[((Q_OFF + reg * 10240 + h * QK_H + 49 * QK_ST) >> 1) + rem] = 0u;
    }

    // ---- Stage A: stage 51 x-rows as bf16; q-run rows (0-16) pre-scaled ----
    for (int t = tid; t < 51 * 32; t += 512) {
        int row = t >> 5, kq = (t & 31) * 4;
        int run = row >= 34 ? 2 : (row >= 17 ? 1 : 0);
        int r0s = run == 2 ? r0_2 : (run == 1 ? r0_1 : r0_0);
        int gr = r0s + row - run * 17;
        float4 v = *(const float4*)&x[gr * 128 + kq];
        float sc = (row < 17) ? qscale : 1.f;
        uint2 d;
        d.x = (unsigned int)f2bf(v.x * sc) | ((unsigned int)f2bf(v.y * sc) << 16);
        d.y = (unsigned int)f2bf(v.z * sc) | ((unsigned int)f2bf(v.w * sc) << 16);
        *(uint2*)&ldsw[(row * XB_ST + kq) >> 1] = d;
    }
    __syncthreads();

    // ---- Stage B: qkv GEMM (64x384, K=128), table-driven scatter ----
    const unsigned short* stB = &stab[b3 * 384 * 64];
    for (int ntj = 0; ntj < 3; ++ntj) {
        const int C = (wid + ntj * 8) * 16 + l15;
        short8 bf[4];
        const short8* wrow = (const short8*)&wq[C * 128];
#pragma unroll
        for (int ks = 0; ks < 4; ++ks) bf[ks] = wrow[ks * 4 + lq];
        const float b1 = qkv_b[C];
        const float bq = b1 * qscale;
        const ushort4* stRow = (const ushort4*)&stB[C * 64];
#pragma unroll
        for (int mt = 0; mt < 4; ++mt) {
            f32x4 acc = zero;
#pragma unroll
            for (int ks = 0; ks < 4; ++ks) {
                short8 a = *(const short8*)&lds[(mt * 16 + l15) * XB_ST + ks * 32 + lq * 8];
                acc = __builtin_amdgcn_mfma_f32_16x16x32_bf16(a, bf[ks], acc, 0, 0, 0);
            }
            ushort4 e = stRow[mt * 4 + lq];
            int Rb = mt * 16 + lq * 4;
            lds[e.x] = f2bf(acc[0] + (Rb + 0 < 17 ? bq : b1));
            lds[e.y] = f2bf(acc[1] + (Rb + 1 < 17 ? bq : b1));
            lds[e.z] = f2bf(acc[2] + (Rb + 2 < 17 ? bq : b1));
            lds[e.w] = f2bf(acc[3] + (Rb + 3 < 17 ? bq : b1));
        }
    }
    __syncthreads();

    // ---- Stage C: QK^T MFMA, barrier (P overlays q/k), softmax -> P ----
    const int h = wid >> 1;
    {
        const int ihalf = wid & 1;
        short8 kf[4];
#pragma unroll
        for (int jt = 0; jt < 4; ++jt)
            kf[jt] = *(const short8*)&lds[K_OFF + h * QK_H + (jt * 16 + l15) * QK_ST + lq * 8];
        f32x4 acc[2][4];
#pragma unroll
        for (int it = 0; it < 2; ++it) {
            short8 qf = *(const short8*)&lds[Q_OFF + h * QK_H + (ihalf * 32 + it * 16 + l15) * QK_ST + lq * 8];
#pragma unroll
            for (int jt = 0; jt < 4; ++jt)
                acc[it][jt] = __builtin_amdgcn_mfma_f32_16x16x32_bf16(qf, kf[jt], zero, 0, 0, 0);
        }
        __syncthreads();          // q/k reads done; P may overlay
        const float* Tb = T + (((b & 63) * 4 + h) << 12);
#pragma unroll
        for (int it = 0; it < 2; ++it)
#pragma unroll
        for (int r = 0; r < 4; ++r) {
            int i = ihalf * 32 + it * 16 + lq * 4 + r;
            const float* Trow = Tb + i * 64 + l15;
            float s0 = acc[it][0][r] + Trow[0];
            float s1 = acc[it][1][r] + Trow[16];
            float s2 = acc[it][2][r] + Trow[32];
            float s3 = acc[it][3][r] + Trow[48];
            float m = fmaxf(fmaxf(s0, s1), fmaxf(s2, s3));
            m = fmaxf(m, __shfl_xor(m, 1));
            m = fmaxf(m, __shfl_xor(m, 2));
            m = fmaxf(m, __shfl_xor(m, 4));
            m = fmaxf(m, __shfl_xor(m, 8));
            float e0 = exp2f(s0 - m), e1 = exp2f(s1 - m);
            float e2 = exp2f(s2 - m), e3 = exp2f(s3 - m);
            float sum = e0 + e1 + e2 + e3;
            sum += __shfl_xor(sum, 1);
            sum += __shfl_xor(sum, 2);
            sum += __shfl_xor(sum, 4);
            sum += __shfl_xor(sum, 8);
            float inv = 1.f / sum;
            int pb = P_OFF + (h * 64 + i) * P_ST + l15;
            lds[pb +  0] = f2bf(e0 * inv);
            lds[pb + 16] = f2bf(e1 * inv);
            lds[pb + 32] = f2bf(e2 * inv);
            lds[pb + 48] = f2bf(e3 * inv);
        }
    }
    __syncthreads();

    // ---- Stage D: PV -> Aout (overlays xb) ----
    {
        const int dt = wid & 1;
        const int vbase = VT_OFF + h * VT_H + (dt * 16 + l15) * VT_ST + lq * 8;
        short8 vf0 = *(const short8*)&lds[vbase];
        short8 vf1 = *(const short8*)&lds[vbase + 32];
#pragma unroll
        for (int mt = 0; mt < 4; ++mt) {
            int pbase = P_OFF + (h * 64 + mt * 16 + l15) * P_ST + lq * 8;
            short8 a0 = *(const short8*)&lds[pbase];
            short8 a1 = *(const short8*)&lds[pbase + 32];
            f32x4 acc = __builtin_amdgcn_mfma_f32_16x16x32_bf16(a0, vf0, zero, 0, 0, 0);
            acc = __builtin_amdgcn_mfma_f32_16x16x32_bf16(a1, vf1, acc, 0, 0, 0);
            int i0 = mt * 16 + lq * 4;
            int abase = AOUT_OFF + h * 32 + dt * 16 + l15;
            if (i0 + 0 < 49) lds[abase + (i0 + 0) * XB_ST] = f2bf(acc[0]);
            if (i0 + 1 < 49) lds[abase + (i0 + 1) * XB_ST] = f2bf(acc[1]);
            if (i0 + 2 < 49) lds[abase + (i0 + 2) * XB_ST] = f2bf(acc[2]);
            if (i0 + 3 < 49) lds[abase + (i0 + 3) * XB_ST] = f2bf(acc[3]);
        }
    }
    // hoist stage-E global loads before the barrier
    const int Cp = wid * 16 + l15;
    short8 pf[4];
#pragma unroll
    for (int ks = 0; ks < 4; ++ks)
        pf[ks] = *(const short8*)&pw[Cp * 128 + ks * 32 + lq * 8];
    const float pbv = proj_b[Cp];
    __syncthreads();

    // ---- Stage E: proj + bias -> out ----
#pragma unroll
    for (int mt = 0; mt < 4; ++mt) {
        f32x4 acc = zero;
#pragma unroll
        for (int ks = 0; ks < 4; ++ks) {
            short8 a = *(const short8*)&lds[AOUT_OFF + (mt * 16 + l15) * XB_ST + ks * 32 + lq * 8];
            acc = __builtin_amdgcn_mfma_f32_16x16x32_bf16(a, pf[ks], acc, 0, 0, 0);
        }
#pragma unroll
        for (int r = 0; r < 4; ++r) {
            int R = mt * 16 + lq * 4 + r;
            if (R < 49)
                out[(b * 49 + R) * 128 + Cp] = acc[r] + pbv;
        }
    }
}

extern "C" void kernel_launch(void* const* d_in, const int* in_sizes, int n_in,
                              void* d_out, int out_size, void* d_ws, size_t ws_size,
                              hipStream_t stream) {
    const float* x      = (const float*)d_in[0];
    const float* mask   = (const float*)d_in[1];
    const float* qkv_w  = (const float*)d_in[2];
    const float* qkv_b  = (const float*)d_in[3];
    const float* proj_w = (const float*)d_in[4];
    const float* proj_b = (const float*)d_in[5];
    const float* rpt    = (const float*)d_in[6];
    float* out = (float*)d_out;

    unsigned short* wq   = (unsigned short*)d_ws;
    unsigned short* pw   = (unsigned short*)((char*)d_ws + 98304);
    unsigned short* stab = (unsigned short*)((char*)d_ws + 131072);
    float*          T    = (float*)((char*)d_ws + 278528);

    prep<<<4640, 256, 0, stream>>>(qkv_w, proj_w, mask, rpt, wq, pw, stab, T);
    winattn<<<8192, 512, 0, stream>>>(x, wq, pw, stab, T, qkv_b, proj_b, out);
}